// Round 7
// baseline (73.102 us; speedup 1.0000x reference)
//
#include <hip/hip_runtime.h>

typedef __attribute__((ext_vector_type(8))) short bf16x8;
typedef __attribute__((ext_vector_type(4))) float f32x4;
typedef __attribute__((ext_vector_type(4))) unsigned short us4;

__device__ __forceinline__ unsigned short f2bf(float f) {
    unsigned int u = __builtin_bit_cast(unsigned int, f);
    unsigned int r = (u + 0x7fffu + ((u >> 16) & 1u)) >> 16;
    return (unsigned short)r;
}

// ---------------------------------------------------------------------------
// Fused independent prep: rc projections, tg mean, y->bf16, W->bf16 transposed.
// (validated R3 kernel, unchanged)
__global__ __launch_bounds__(256) void k_aux(
    const float* __restrict__ idx_emb, const float* __restrict__ msg_W1,
    float* __restrict__ rc,
    const float* __restrict__ t_grad, float* __restrict__ tg,
    const float* __restrict__ y, unsigned short* __restrict__ xbf,
    const float* __restrict__ gnn_W, unsigned short* __restrict__ WbfT) {
    __shared__ float red[4][64];
    int bx = blockIdx.x, t = threadIdx.x;
    if (bx < 128) {
        int tid = bx * 256 + t;
        int h = tid & 7, n = (tid >> 3) & 1023, t_ = (tid >> 13) & 1, k = tid >> 14;
        const float* wv = msg_W1 + k * 1032 + h * 129 + 1 + t_ * 64;
        const float* e = idx_emb + n * 64;
        float s = 0.f;
#pragma unroll
        for (int d = 0; d < 64; ++d) s += e[d] * wv[d];
        rc[(k * 2 + t_) * 8192 + n * 8 + h] = s;
    } else if (bx < 144) {
        int jl = t & 63, sg = t >> 6;
        int j = (bx - 128) * 64 + jl;
        float acc = 0.f;
        for (int i = 0; i < 256; ++i) acc += t_grad[(sg * 256 + i) * 1024 + j];
        red[sg][jl] = acc;
        __syncthreads();
        if (sg == 0)
            tg[j] = (red[0][jl] + red[1][jl] + red[2][jl] + red[3][jl]) * (1.f / 1024.f);
    } else if (bx < 160) {
        int base = (bx - 144) * 4096 + t;
#pragma unroll
        for (int p = 0; p < 16; ++p) xbf[base + p * 256] = f2bf(y[base + p * 256]);
    } else if (bx < 175) {
        int wi = bx - 160;                      // l*5 + j
        const float* src = gnn_W + wi * 4096;
        unsigned short* dst = WbfT + wi * 4096; // [c][d] = W[d][c]
        int c = t & 63, dg = t >> 6;
#pragma unroll
        for (int p = 0; p < 16; ++p) {
            int d = dg + p * 4;
            dst[c * 64 + d] = f2bf(src[d * 64 + c]);
        }
    }
}

// ---------------------------------------------------------------------------
// Fused msg-MLP + bf16 convert + transpose. grid (16 mt, 16 nt, 2 z).
// (validated R3 kernel, unchanged)
__global__ __launch_bounds__(256) void k_msgcvt(
    const float* __restrict__ adj, const float* __restrict__ adj_deriv,
    const float* __restrict__ W1, const float* __restrict__ b1,
    const float* __restrict__ W2, const float* __restrict__ b2,
    const float* __restrict__ W3, const float* __restrict__ b3,
    const float* __restrict__ rc, unsigned short* __restrict__ Abf) {
    int mt = blockIdx.x, nt = blockIdx.y, z = blockIdx.z;
    const float* A = z ? adj_deriv : adj;
    unsigned short* D0 = Abf + z * 2097152;
    unsigned short* D1 = D0 + 1048576;
    int k = z;

    float wa[8], b1v[8], w2[64], b2v[8], w3v[8];
#pragma unroll
    for (int h = 0; h < 8; ++h) {
        wa[h]  = W1[k * 1032 + h * 129];
        b1v[h] = b1[k * 8 + h];
        b2v[h] = b2[k * 8 + h];
        w3v[h] = W3[k * 8 + h];
    }
#pragma unroll
    for (int i = 0; i < 64; ++i) w2[i] = W2[k * 64 + i];
    float b3v = b3[k];

    int t = threadIdx.x;
    int c = t & 63, rg = t >> 6;
    const float* colp = rc + (k * 2 + 1) * 8192 + (mt * 64 + c) * 8;
    float cm[8];
    *(float4*)&cm[0] = *(const float4*)colp;
    *(float4*)&cm[4] = *(const float4*)(colp + 4);
    const float* rowp = rc + (k * 2) * 8192 + (nt * 64) * 8;

    __shared__ unsigned short tile[64][65];
#pragma unroll
    for (int p = 0; p < 16; ++p) {
        int r = rg + 4 * p;                     // wave-uniform row
        float av = A[(nt * 64 + r) * 1024 + mt * 64 + c];
        float rn[8];
        *(float4*)&rn[0] = *(const float4*)(rowp + r * 8);
        *(float4*)&rn[4] = *(const float4*)(rowp + r * 8 + 4);
        float h1[8];
#pragma unroll
        for (int h = 0; h < 8; ++h) {
            float v = av * wa[h] + rn[h] + cm[h] + b1v[h];
            h1[h] = v > 0.f ? v : 0.f;
        }
        float o = b3v;
#pragma unroll
        for (int kk = 0; kk < 8; ++kk) {
            float s = b2v[kk];
#pragma unroll
            for (int h = 0; h < 8; ++h) s += h1[h] * w2[kk * 8 + h];
            s = s > 0.f ? s : 0.f;
            o += s * w3v[kk];
        }
        unsigned short us = f2bf(o);
        D0[(nt * 64 + r) * 1024 + mt * 64 + c] = us;
        tile[r][c] = us;
    }
    __syncthreads();
#pragma unroll
    for (int p = 0; p < 16; ++p) {
        int r = rg + 4 * p;
        D1[(mt * 64 + r) * 1024 + nt * 64 + c] = tile[c][r];
    }
}

// ---------------------------------------------------------------------------
// Layer kernel: [x-window prologue] + u-phase (MFMA -> swizzled LDS) +
// 4-term main GEMM. grid (16 nt, 16 ms), 256 threads (4 waves).
// L==0: x-window loaded from xbf (global).
// L>0 : x-window = relu(sum_s Pin[s] + u4in + bprev) over rows [m0,m0+64)
//       (the validated k_post formula, computed block-locally into LDS).
template<int L>
__global__ __launch_bounds__(256) void k_layer(
    const unsigned short* __restrict__ Abf,
    const unsigned short* __restrict__ xbf,
    const float* __restrict__ Pin, const float* __restrict__ u4in,
    const float* __restrict__ bprev,
    const unsigned short* __restrict__ WT,    // this layer: [5][64 c][64 d]
    float* __restrict__ u4out, float* __restrict__ Pout) {
    int nt = blockIdx.x, ms = blockIdx.y;
    int t = threadIdx.x, w = t >> 6, l64 = t & 63;
    int lr = l64 & 15, lk = l64 >> 4, klo = 8 * lk;
    int m0 = ms * 64;
    __shared__ unsigned short uTs[16384];    // [4 j][64 c][64 m] bf16, swizzled
    __shared__ unsigned short xs[4096];      // [64 m][64 d] bf16, rows m0..m0+64

    // ---- x-window prologue ----
    if constexpr (L == 0) {
#pragma unroll
        for (int p = 0; p < 2; ++p) {
            int e = (t + p * 256) * 8;
            *(bf16x8*)&xs[e] = *(const bf16x8*)&xbf[m0 * 64 + e];
        }
    } else {
#pragma unroll
        for (int p = 0; p < 4; ++p) {
            int q = t + p * 256;             // float4 id in [0,1024)
            int row = q >> 4, c4 = (q & 15) * 4;
            int gi = (m0 + row) * 64 + c4;
            float4 acc4 = *(const float4*)&u4in[gi];
            float4 b4 = *(const float4*)&bprev[c4];
            acc4.x += b4.x; acc4.y += b4.y; acc4.z += b4.z; acc4.w += b4.w;
#pragma unroll
            for (int s = 0; s < 16; ++s) {
                float4 pv = *(const float4*)&Pin[s * 65536 + gi];
                acc4.x += pv.x; acc4.y += pv.y; acc4.z += pv.z; acc4.w += pv.w;
            }
            us4 pk;
            pk[0] = f2bf(fmaxf(acc4.x, 0.f));
            pk[1] = f2bf(fmaxf(acc4.y, 0.f));
            pk[2] = f2bf(fmaxf(acc4.z, 0.f));
            pk[3] = f2bf(fmaxf(acc4.w, 0.f));
            *(us4*)&xs[row * 64 + c4] = pk;
        }
    }
    __syncthreads();

    // ---- u-phase: u[m][c] = sum_d x[m][d] W[d][c] via MFMA (x from LDS) ----
    int mloc = w * 16 + lr;
    bf16x8 xa0 = *(const bf16x8*)&xs[mloc * 64 + klo];
    bf16x8 xa1 = *(const bf16x8*)&xs[mloc * 64 + 32 + klo];
    int njmax = (nt == 0) ? 5 : 4;
    for (int j = 0; j < njmax; ++j) {
        f32x4 au[4];
#pragma unroll
        for (int cf = 0; cf < 4; ++cf) au[cf] = (f32x4){0.f, 0.f, 0.f, 0.f};
#pragma unroll
        for (int cf = 0; cf < 4; ++cf) {
            bf16x8 wf0 = *(const bf16x8*)&WT[(j * 64 + cf * 16 + lr) * 64 + klo];
            bf16x8 wf1 = *(const bf16x8*)&WT[(j * 64 + cf * 16 + lr) * 64 + 32 + klo];
            au[cf] = __builtin_amdgcn_mfma_f32_16x16x32_bf16(xa0, wf0, au[cf], 0, 0, 0);
            au[cf] = __builtin_amdgcn_mfma_f32_16x16x32_bf16(xa1, wf1, au[cf], 0, 0, 0);
        }
        if (j < 4) {
#pragma unroll
            for (int cf = 0; cf < 4; ++cf) {
                int cc = cf * 16 + lr;
                us4 pk;
                pk[0] = f2bf(au[cf][0]); pk[1] = f2bf(au[cf][1]);
                pk[2] = f2bf(au[cf][2]); pk[3] = f2bf(au[cf][3]);
                int off = ((j * 64 + cc) * 64 + w * 16 + lk * 4) * 2;
                *(us4*)((char*)uTs + (off ^ ((cc & 7) << 4))) = pk;
            }
        } else {
#pragma unroll
            for (int cf = 0; cf < 4; ++cf)
#pragma unroll
                for (int r = 0; r < 4; ++r)
                    u4out[(m0 + w * 16 + lk * 4 + r) * 64 + cf * 16 + lr] = au[cf][r];
        }
    }
    __syncthreads();

    // ---- main: P = a@u0 + aT@u1 + ad@u2 + adT@u3 over this m-window ----
    f32x4 acc[4];
#pragma unroll
    for (int cf = 0; cf < 4; ++cf) acc[cf] = (f32x4){0.f, 0.f, 0.f, 0.f};
    int arow = nt * 64 + w * 16 + lr;
#pragma unroll
    for (int j = 0; j < 4; ++j) {
#pragma unroll
        for (int kk = 0; kk < 2; ++kk) {
            bf16x8 af = *(const bf16x8*)&Abf[j * 1048576 + arow * 1024 + m0 + kk * 32 + klo];
#pragma unroll
            for (int cf = 0; cf < 4; ++cf) {
                int cc = cf * 16 + lr;
                int off = ((j * 64 + cc) * 64 + kk * 32 + klo) * 2;
                bf16x8 bfr = *(const bf16x8*)((char*)uTs + (off ^ ((cc & 7) << 4)));
                acc[cf] = __builtin_amdgcn_mfma_f32_16x16x32_bf16(af, bfr, acc[cf], 0, 0, 0);
            }
        }
    }
    float* Pp = Pout + ms * 65536;
    int nbase = nt * 64 + w * 16 + lk * 4;
#pragma unroll
    for (int cf = 0; cf < 4; ++cf)
#pragma unroll
        for (int r = 0; r < 4; ++r)
            Pp[(nbase + r) * 64 + cf * 16 + lr] = acc[cf][r];
}

// ---------------------------------------------------------------------------
// Final: out = tg[n] * (sum_s P[s] + u4 + b)   (validated R3 k_post, mode 2)
__global__ void k_final(const float* __restrict__ P, const float* __restrict__ u4,
                        const float* __restrict__ b, const float* __restrict__ tg,
                        float* __restrict__ out) {
    int idx = blockIdx.x * 256 + threadIdx.x;
    int n = idx >> 6, c = idx & 63;
    float s = u4[idx] + b[c];
#pragma unroll
    for (int k = 0; k < 16; ++k) s += P[k * 65536 + idx];
    out[idx] = tg[n] * s;
}

// ---------------------------------------------------------------------------
extern "C" void kernel_launch(void* const* d_in, const int* in_sizes, int n_in,
                              void* d_out, int out_size, void* d_ws, size_t ws_size,
                              hipStream_t stream) {
    const float* y         = (const float*)d_in[0];
    const float* adj       = (const float*)d_in[1];
    const float* adj_deriv = (const float*)d_in[2];
    const float* t_grad    = (const float*)d_in[3];
    const float* idx_emb   = (const float*)d_in[4];
    const float* msg_W1    = (const float*)d_in[5];
    const float* msg_b1    = (const float*)d_in[6];
    const float* msg_W2    = (const float*)d_in[7];
    const float* msg_b2    = (const float*)d_in[8];
    const float* msg_W3    = (const float*)d_in[9];
    const float* msg_b3    = (const float*)d_in[10];
    const float* gnn_W     = (const float*)d_in[11];
    const float* gnn_b     = (const float*)d_in[12];
    float* outp = (float*)d_out;

    float* ws = (float*)d_ws;
    float* rc   = ws;                                        // 32768 f
    float* tg   = ws + 32768;                                // 1024 f
    float* u4A  = ws + 33792;                                // 65536 f
    float* u4B  = ws + 99328;                                // 65536 f
    float* PA   = ws + 164864;                               // 1048576 f
    float* PB   = ws + 1213440;                              // 1048576 f
    unsigned short* xbf  = (unsigned short*)(ws + 2262016);  // 65536 us
    unsigned short* WbfT = (unsigned short*)(ws + 2294784);  // 61440 us
    unsigned short* Abf  = (unsigned short*)(ws + 2325504);  // 4194304 us
    // end: 4422656 floats = 17.7 MB

    k_aux<<<175, 256, 0, stream>>>(idx_emb, msg_W1, rc, t_grad, tg,
                                   y, xbf, gnn_W, WbfT);
    k_msgcvt<<<dim3(16, 16, 2), 256, 0, stream>>>(adj, adj_deriv,
                                                  msg_W1, msg_b1, msg_W2, msg_b2,
                                                  msg_W3, msg_b3, rc, Abf);
    k_layer<0><<<dim3(16, 16), 256, 0, stream>>>(Abf, xbf, PA, u4A, gnn_b,
                                                 WbfT, u4A, PA);
    k_layer<1><<<dim3(16, 16), 256, 0, stream>>>(Abf, xbf, PA, u4A, gnn_b,
                                                 WbfT + 20480, u4B, PB);
    k_layer<2><<<dim3(16, 16), 256, 0, stream>>>(Abf, xbf, PB, u4B, gnn_b + 64,
                                                 WbfT + 40960, u4A, PA);
    k_final<<<256, 256, 0, stream>>>(PA, u4A, gnn_b + 128, tg, outp);
}